// Round 1
// baseline (674.813 us; speedup 1.0000x reference)
//
#include <hip/hip_runtime.h>
#include <hip/hip_bf16.h>

// OneToOneLinear: out[n] = prod_f sqrt(sigmoid(10*(x[n,f]*w[f]+b[f])))
// Identity: sqrt(sigmoid(z)) = rsqrt(1 + exp(-z)), exp(-z) = exp2(x*a + d)
// with a = -10*w*log2(e), d = -10*b*log2(e) (loop-invariant per column).

__device__ __forceinline__ float fast_exp2(float x) {
#if __has_builtin(__builtin_amdgcn_exp2f)
    return __builtin_amdgcn_exp2f(x);
#else
    return exp2f(x);
#endif
}

__device__ __forceinline__ float fast_rsqrt(float x) {
#if __has_builtin(__builtin_amdgcn_rsqf)
    return __builtin_amdgcn_rsqf(x);
#else
    return rsqrtf(x);
#endif
}

// Layout: row = 64 floats = 16 float4. Lane i of a wave loads float4 #(base+i)
// -> one wave load = 64 lanes x 16B = 1 KiB contiguous = 4 complete rows.
// Lanes (g*16 .. g*16+15) share row (f>>4); column group = (tid & 15)*4 is
// loop-invariant (grid stride is a multiple of 64), so each lane keeps its
// 4 (a,d) coefficient pairs in registers.
__global__ __launch_bounds__(256) void one2one_prod_kernel(
    const float* __restrict__ in,   // [N, 64] row-major
    const float* __restrict__ w,    // [64]
    const float* __restrict__ b,    // [64]
    float* __restrict__ out,        // [N]
    long long total_f4)             // N * 16
{
    const float NEG10LOG2E = -10.0f * 1.44269504088896340736f;
    const int grp = threadIdx.x & 15;   // which float4 within the row
    const int c0 = grp * 4;

    const float4 wv = *(const float4*)(w + c0);
    const float4 bv = *(const float4*)(b + c0);
    const float a0 = NEG10LOG2E * wv.x, a1 = NEG10LOG2E * wv.y;
    const float a2 = NEG10LOG2E * wv.z, a3 = NEG10LOG2E * wv.w;
    const float d0 = NEG10LOG2E * bv.x, d1 = NEG10LOG2E * bv.y;
    const float d2 = NEG10LOG2E * bv.z, d3 = NEG10LOG2E * bv.w;

    const float4* __restrict__ in4 = (const float4*)in;
    const long long stride = (long long)gridDim.x * blockDim.x;

    for (long long f = (long long)blockIdx.x * blockDim.x + threadIdx.x;
         f < total_f4; f += stride) {
        float4 x = in4[f];

        float e0 = fast_exp2(fmaf(x.x, a0, d0));
        float e1 = fast_exp2(fmaf(x.y, a1, d1));
        float e2 = fast_exp2(fmaf(x.z, a2, d2));
        float e3 = fast_exp2(fmaf(x.w, a3, d3));

        float r0 = fast_rsqrt(1.0f + e0);
        float r1 = fast_rsqrt(1.0f + e1);
        float r2 = fast_rsqrt(1.0f + e2);
        float r3 = fast_rsqrt(1.0f + e3);

        float p = (r0 * r1) * (r2 * r3);

        // product-reduce across the 16 lanes sharing this row (butterfly)
        p *= __shfl_xor(p, 1, 64);
        p *= __shfl_xor(p, 2, 64);
        p *= __shfl_xor(p, 4, 64);
        p *= __shfl_xor(p, 8, 64);

        if (grp == 0) {
            out[f >> 4] = p;
        }
    }
}

extern "C" void kernel_launch(void* const* d_in, const int* in_sizes, int n_in,
                              void* d_out, int out_size, void* d_ws, size_t ws_size,
                              hipStream_t stream) {
    const float* in = (const float*)d_in[0];   // [N, 64] fp32
    const float* w  = (const float*)d_in[1];   // [64] fp32
    const float* b  = (const float*)d_in[2];   // [64] fp32
    float* out = (float*)d_out;                // [N] fp32

    const long long total_f4 = (long long)in_sizes[0] / 4;  // N*16

    const int block = 256;
    const int grid = 8192;  // 2M threads, 16 f4-iters each; 32 waves/CU occupancy
    hipLaunchKernelGGL(one2one_prod_kernel, dim3(grid), dim3(block), 0, stream,
                       in, w, b, out, total_f4);
}

// Round 3
// 666.681 us; speedup vs baseline: 1.0122x; 1.0122x over previous
//
#include <hip/hip_runtime.h>

// OneToOneLinear: out[n] = prod_f sqrt(sigmoid(10*(x[n,f]*w[f]+b[f])))
// sqrt(sigmoid(z)) = rsqrt(1+exp(-z));  prod_f rsqrt(1+e_f) = rsqrt(prod_f (1+e_f))
// exp(-10(x*w+b)) = exp2(x*a + d), a = -10*w*log2(e), d = -10*b*log2(e).
// If prod(1+e) overflows fp32 -> inf -> v_rsq gives 0; true value < 1e-19,
// far below the 5.7e-10 absmax threshold. Safe.

typedef float vfloat4 __attribute__((ext_vector_type(4)));  // native vec for nontemporal builtin

__device__ __forceinline__ float exp2_hw(float x) {
    float r; asm("v_exp_f32 %0, %1" : "=v"(r) : "v"(x)); return r;   // 2^x, 1 instr
}
__device__ __forceinline__ float rsq_hw(float x) {
    float r; asm("v_rsq_f32 %0, %1" : "=v"(r) : "v"(x)); return r;   // 1/sqrt, 1 instr
}

// Butterfly product over the 16-lane group via ds_swizzle (BitMode:
// offset = xor_mask<<10 | or_mask<<5 | and_mask; and=0x1F keeps it within
// 32-lane halves, xor<16 never crosses the 16-group boundary).
template <int PAT>
__device__ __forceinline__ float bfly_mul(float p) {
    int q = __builtin_amdgcn_ds_swizzle(__builtin_bit_cast(int, p), PAT);
    return p * __builtin_bit_cast(float, q);
}
__device__ __forceinline__ float group16_prod(float p) {
    p = bfly_mul<0x041F>(p);   // xor 1
    p = bfly_mul<0x081F>(p);   // xor 2
    p = bfly_mul<0x101F>(p);   // xor 4
    p = bfly_mul<0x201F>(p);   // xor 8
    return p;
}

// Row = 64 floats = 16 float4. Lane i loads float4 #(base+i): one wave load
// = 64 x 16B = 1 KiB contiguous = 4 full rows. Lane's column group
// (threadIdx.x & 15) is loop-invariant -> (a,d) coeffs live in registers.
__global__ __launch_bounds__(256) void one2one_prod_kernel(
    const vfloat4* __restrict__ in4, // [N*16]
    const float*   __restrict__ w,   // [64]
    const float*   __restrict__ b,   // [64]
    float*         __restrict__ out, // [N]
    int total_f4)                    // N*16 = 2^25 (fits int; bytes = 2^29)
{
    const float C = -14.4269504088896340736f;  // -10 * log2(e)
    const int grp = threadIdx.x & 15;

    const vfloat4 wv = ((const vfloat4*)w)[grp];
    const vfloat4 bv = ((const vfloat4*)b)[grp];
    const float a0 = C * wv.x, a1 = C * wv.y, a2 = C * wv.z, a3 = C * wv.w;
    const float d0 = C * bv.x, d1 = C * bv.y, d2 = C * bv.z, d3 = C * bv.w;

    const int stride = gridDim.x * blockDim.x;
    int f = blockIdx.x * blockDim.x + threadIdx.x;

    // Unroll x2: two independent load->exp->product->butterfly chains.
    for (; f + stride < total_f4; f += 2 * stride) {
        vfloat4 x = __builtin_nontemporal_load(&in4[f]);
        vfloat4 y = __builtin_nontemporal_load(&in4[f + stride]);

        float px = (1.0f + exp2_hw(fmaf(x.x, a0, d0)))
                 * (1.0f + exp2_hw(fmaf(x.y, a1, d1)))
                 * (1.0f + exp2_hw(fmaf(x.z, a2, d2)))
                 * (1.0f + exp2_hw(fmaf(x.w, a3, d3)));
        float py = (1.0f + exp2_hw(fmaf(y.x, a0, d0)))
                 * (1.0f + exp2_hw(fmaf(y.y, a1, d1)))
                 * (1.0f + exp2_hw(fmaf(y.z, a2, d2)))
                 * (1.0f + exp2_hw(fmaf(y.w, a3, d3)));

        px = group16_prod(px);
        py = group16_prod(py);

        if (grp == 0) {
            out[f >> 4]            = rsq_hw(px);
            out[(f + stride) >> 4] = rsq_hw(py);
        }
    }
    if (f < total_f4) {  // tail (not taken for N=2^21: exactly 16 passes)
        vfloat4 x = __builtin_nontemporal_load(&in4[f]);
        float px = (1.0f + exp2_hw(fmaf(x.x, a0, d0)))
                 * (1.0f + exp2_hw(fmaf(x.y, a1, d1)))
                 * (1.0f + exp2_hw(fmaf(x.z, a2, d2)))
                 * (1.0f + exp2_hw(fmaf(x.w, a3, d3)));
        px = group16_prod(px);
        if (grp == 0) out[f >> 4] = rsq_hw(px);
    }
}

extern "C" void kernel_launch(void* const* d_in, const int* in_sizes, int n_in,
                              void* d_out, int out_size, void* d_ws, size_t ws_size,
                              hipStream_t stream) {
    const vfloat4* in4 = (const vfloat4*)d_in[0];  // [N,64] fp32
    const float*   w   = (const float*)d_in[1];    // [64]
    const float*   b   = (const float*)d_in[2];    // [64]
    float* out = (float*)d_out;                    // [N]

    const int total_f4 = in_sizes[0] / 4;          // N*16

    const int block = 256;
    const int grid  = 8192;  // 2M threads; 16 f4-passes -> 8 unrolled iters
    hipLaunchKernelGGL(one2one_prod_kernel, dim3(grid), dim3(block), 0, stream,
                       in4, w, b, out, total_f4);
}